// Round 4
// baseline (3047.100 us; speedup 1.0000x reference)
//
#include <hip/hip_runtime.h>
#include <hip/hip_bf16.h>

// GCN 2-layer fused pipeline for MI355X.
// Sizes fixed per reference file.
constexpr int N_NODES = 100000;
constexpr int N_EDGES = 3200000;
constexpr int F1 = 16;   // hidden dim
constexpr int FIN = 5;   // input dim

// NOTE: harness passes integer inputs as int32 (NOT the reference's int64).
// Round-3 core dump was caused by casting edge_index to long long.

// ---- Kernel 1: in-degree count over dst (self-loop added later as +1) ----
__global__ __launch_bounds__(256) void deg_kernel(const int* __restrict__ dst,
                                                  float* __restrict__ deg) {
    int i = blockIdx.x * blockDim.x + threadIdx.x;
    if (i < N_EDGES) atomicAdd(&deg[dst[i]], 1.0f);
}

// ---- Kernel 2: deg -> dinv = rsqrt(deg + 1)  (self-loop) ----
__global__ __launch_bounds__(256) void dinv_kernel(float* __restrict__ deg) {
    int i = blockIdx.x * blockDim.x + threadIdx.x;
    if (i < N_NODES) deg[i] = rsqrtf(deg[i] + 1.0f);
}

// ---- Kernel 3: xw = x @ W1 ; agg seeded with self-loop dinv^2 * xw ----
__global__ __launch_bounds__(256) void xw_kernel(const float* __restrict__ x,
                                                 const float* __restrict__ W1,
                                                 const float* __restrict__ dinv,
                                                 float* __restrict__ xw,
                                                 float* __restrict__ agg) {
    int i = blockIdx.x * blockDim.x + threadIdx.x;
    if (i >= N_NODES) return;
    float xi[FIN];
#pragma unroll
    for (int k = 0; k < FIN; ++k) xi[k] = x[i * FIN + k];
    float d = dinv[i];
    float di2 = d * d;
#pragma unroll
    for (int f = 0; f < F1; ++f) {
        float s = 0.f;
#pragma unroll
        for (int k = 0; k < FIN; ++k) s += xi[k] * W1[k * F1 + f];
        xw[i * F1 + f] = s;
        agg[i * F1 + f] = di2 * s;
    }
}

// ---- Kernel 4: layer-1 edge scatter: agg[dst] += dinv[s]*dinv[d] * xw[src] ----
__global__ __launch_bounds__(256) void agg1_kernel(const int* __restrict__ src,
                                                   const int* __restrict__ dst,
                                                   const float* __restrict__ dinv,
                                                   const float* __restrict__ xw,
                                                   float* __restrict__ agg) {
    int e = blockIdx.x * blockDim.x + threadIdx.x;
    if (e >= N_EDGES) return;
    int s = src[e];
    int d = dst[e];
    float nrm = dinv[s] * dinv[d];
    const float4* xs = (const float4*)(&xw[s * F1]);
    float* ad = &agg[d * F1];
#pragma unroll
    for (int q = 0; q < 4; ++q) {
        float4 v = xs[q];
        atomicAdd(&ad[q * 4 + 0], nrm * v.x);
        atomicAdd(&ad[q * 4 + 1], nrm * v.y);
        atomicAdd(&ad[q * 4 + 2], nrm * v.z);
        atomicAdd(&ad[q * 4 + 3], nrm * v.w);
    }
}

// ---- Kernel 5: z = relu(agg + b1) @ W2  (scalar per node) ----
__global__ __launch_bounds__(256) void z_kernel(const float* __restrict__ agg,
                                                const float* __restrict__ b1,
                                                const float* __restrict__ W2,
                                                float* __restrict__ z) {
    int i = blockIdx.x * blockDim.x + threadIdx.x;
    if (i >= N_NODES) return;
    float s = 0.f;
#pragma unroll
    for (int f = 0; f < F1; ++f) {
        float h = agg[i * F1 + f] + b1[f];
        h = h > 0.f ? h : 0.f;
        s += h * W2[f];
    }
    z[i] = s;
}

// ---- Kernel 6: seed out with self-loop + bias ----
__global__ __launch_bounds__(256) void out_init_kernel(const float* __restrict__ dinv,
                                                       const float* __restrict__ z,
                                                       const float* __restrict__ b2,
                                                       float* __restrict__ out) {
    int i = blockIdx.x * blockDim.x + threadIdx.x;
    if (i < N_NODES) out[i] = dinv[i] * dinv[i] * z[i] + b2[0];
}

// ---- Kernel 7: layer-2 edge scatter (scalar) ----
__global__ __launch_bounds__(256) void agg2_kernel(const int* __restrict__ src,
                                                   const int* __restrict__ dst,
                                                   const float* __restrict__ dinv,
                                                   const float* __restrict__ z,
                                                   float* __restrict__ out) {
    int e = blockIdx.x * blockDim.x + threadIdx.x;
    if (e >= N_EDGES) return;
    int s = src[e];
    int d = dst[e];
    atomicAdd(&out[d], dinv[s] * dinv[d] * z[s]);
}

extern "C" void kernel_launch(void* const* d_in, const int* in_sizes, int n_in,
                              void* d_out, int out_size, void* d_ws, size_t ws_size,
                              hipStream_t stream) {
    const float* x   = (const float*)d_in[0];
    const int*   ei  = (const int*)d_in[1];   // int32 per harness contract
    const float* W1  = (const float*)d_in[2];
    const float* b1  = (const float*)d_in[3];
    const float* W2  = (const float*)d_in[4];
    const float* b2  = (const float*)d_in[5];
    float* out = (float*)d_out;

    // Workspace layout (floats): dinv[N] | xw[N*16] | agg[N*16] | z[N]  (~13.6 MB)
    float* ws   = (float*)d_ws;
    float* dinv = ws;
    float* xw   = ws + N_NODES;
    float* agg  = ws + N_NODES + 16 * N_NODES;
    float* z    = ws + N_NODES + 32 * N_NODES;

    const int* src = ei;            // edge_index[0]
    const int* dst = ei + N_EDGES;  // edge_index[1]

    const int TB = 256;
    int gN = (N_NODES + TB - 1) / TB;
    int gE = (N_EDGES + TB - 1) / TB;

    hipMemsetAsync(dinv, 0, N_NODES * sizeof(float), stream);
    deg_kernel<<<gE, TB, 0, stream>>>(dst, dinv);
    dinv_kernel<<<gN, TB, 0, stream>>>(dinv);
    xw_kernel<<<gN, TB, 0, stream>>>(x, W1, dinv, xw, agg);
    agg1_kernel<<<gE, TB, 0, stream>>>(src, dst, dinv, xw, agg);
    z_kernel<<<gN, TB, 0, stream>>>(agg, b1, W2, z);
    out_init_kernel<<<gN, TB, 0, stream>>>(dinv, z, b2, out);
    agg2_kernel<<<gE, TB, 0, stream>>>(src, dst, dinv, z, out);
}

// Round 11
// 652.352 us; speedup vs baseline: 4.6709x; 4.6709x over previous
//
#include <hip/hip_runtime.h>
#include <hip/hip_bf16.h>

// GCN 2-layer via counting-sort CSR + gather (no float atomics).
// Round-4 evidence: 51.2M float far-atomics in agg1 = 1.6 GB WRITE_SIZE,
// 19.4 G atomics/s wall, 2634 us. Gather formulation removes them.
constexpr int N_NODES = 100000;
constexpr int N_EDGES = 3200000;
constexpr int F1 = 16;   // hidden dim
constexpr int FIN = 5;   // input dim

// ---- 1: histogram of dst (in-degree counts, int atomics) ----
__global__ __launch_bounds__(256) void hist_kernel(const int* __restrict__ dst,
                                                   int* __restrict__ cnt) {
    int i = blockIdx.x * blockDim.x + threadIdx.x;
    if (i < N_EDGES) atomicAdd(&cnt[dst[i]], 1);
}

// ---- 2: single-block scan: cnt -> exclusive offsets (cursor), dinv ----
__global__ __launch_bounds__(1024) void scan_kernel(const int* __restrict__ cnt,
                                                    int* __restrict__ cursor,
                                                    float* __restrict__ dinv) {
    __shared__ int wsum[16];
    __shared__ int woff[16];
    __shared__ int chunk_total_s;
    int tid  = threadIdx.x;
    int lane = tid & 63;
    int wid  = tid >> 6;
    int running = 0;
    for (int base = 0; base < N_NODES; base += 1024) {
        int i = base + tid;
        int v = (i < N_NODES) ? cnt[i] : 0;
        // wave-level inclusive scan (no barriers)
        int s = v;
#pragma unroll
        for (int d = 1; d < 64; d <<= 1) {
            int t = __shfl_up(s, d);
            if (lane >= d) s += t;
        }
        if (lane == 63) wsum[wid] = s;
        __syncthreads();
        if (wid == 0) {
            int wv = (lane < 16) ? wsum[lane] : 0;
            int ss = wv;
#pragma unroll
            for (int d = 1; d < 16; d <<= 1) {
                int t = __shfl_up(ss, d);
                if (lane >= d) ss += t;
            }
            if (lane < 16) woff[lane] = ss - wv;  // exclusive wave offset
            if (lane == 15) chunk_total_s = ss;
        }
        __syncthreads();
        if (i < N_NODES) {
            int excl = running + woff[wid] + (s - v);
            cursor[i] = excl;
            dinv[i] = rsqrtf((float)v + 1.0f);  // +1 self-loop
        }
        running += chunk_total_s;
        __syncthreads();  // protect wsum/chunk_total for next chunk
    }
}

// ---- 3: scatter edges into CSR buckets (returning int atomics) ----
// After this kernel cursor[d] == end offset of node d; start = end - cnt[d].
__global__ __launch_bounds__(256) void scatter_kernel(const int* __restrict__ src,
                                                      const int* __restrict__ dst,
                                                      int* __restrict__ cursor,
                                                      int* __restrict__ csr_src) {
    int i = blockIdx.x * blockDim.x + threadIdx.x;
    if (i < N_EDGES) {
        int pos = atomicAdd(&cursor[dst[i]], 1);
        csr_src[pos] = src[i];
    }
}

// ---- 4: layer-1 gather: wave per node. aggx = di2*x[d] + sum nrm*x[s];
//         z[d] = relu(aggx@W1 + b1) @ W2   (aggregation commutes with W1) ----
__global__ __launch_bounds__(256) void gather1_kernel(const int* __restrict__ csr_src,
                                                      const int* __restrict__ cursor,
                                                      const int* __restrict__ cnt,
                                                      const float* __restrict__ dinv,
                                                      const float* __restrict__ x,
                                                      const float* __restrict__ W1,
                                                      const float* __restrict__ b1,
                                                      const float* __restrict__ W2,
                                                      float* __restrict__ z) {
    int lane = threadIdx.x & 63;
    int wid  = threadIdx.x >> 6;
    int d = blockIdx.x * 4 + wid;
    if (d >= N_NODES) return;
    int end   = cursor[d];
    int n     = cnt[d];
    int start = end - n;
    float dd = dinv[d];
    float a[FIN] = {0.f, 0.f, 0.f, 0.f, 0.f};
    if (lane == 0) {
        float di2 = dd * dd;
#pragma unroll
        for (int k = 0; k < FIN; ++k) a[k] = di2 * x[d * FIN + k];
    }
    for (int e = start + lane; e < end; e += 64) {
        int s = csr_src[e];
        float w = dd * dinv[s];
#pragma unroll
        for (int k = 0; k < FIN; ++k) a[k] += w * x[s * FIN + k];
    }
#pragma unroll
    for (int k = 0; k < FIN; ++k) {
#pragma unroll
        for (int m = 1; m < 64; m <<= 1) a[k] += __shfl_xor(a[k], m);
    }
    // lanes 0..15 each produce one hidden feature, then reduce
    float p = 0.f;
    if (lane < F1) {
        float h = b1[lane];
#pragma unroll
        for (int k = 0; k < FIN; ++k) h += a[k] * W1[k * F1 + lane];
        h = fmaxf(h, 0.f);
        p = h * W2[lane];
    }
#pragma unroll
    for (int m = 1; m < 64; m <<= 1) p += __shfl_xor(p, m);
    if (lane == 0) z[d] = p;
}

// ---- 5: layer-2 gather: out[d] = dd*sum(dinv[s]*z[s]) + dd^2*z[d] + b2 ----
__global__ __launch_bounds__(256) void gather2_kernel(const int* __restrict__ csr_src,
                                                      const int* __restrict__ cursor,
                                                      const int* __restrict__ cnt,
                                                      const float* __restrict__ dinv,
                                                      const float* __restrict__ z,
                                                      const float* __restrict__ b2,
                                                      float* __restrict__ out) {
    int lane = threadIdx.x & 63;
    int wid  = threadIdx.x >> 6;
    int d = blockIdx.x * 4 + wid;
    if (d >= N_NODES) return;
    int end   = cursor[d];
    int n     = cnt[d];
    int start = end - n;
    float acc = 0.f;
    for (int e = start + lane; e < end; e += 64) {
        int s = csr_src[e];
        acc += dinv[s] * z[s];
    }
#pragma unroll
    for (int m = 1; m < 64; m <<= 1) acc += __shfl_xor(acc, m);
    if (lane == 0) {
        float dd = dinv[d];
        out[d] = dd * acc + dd * dd * z[d] + b2[0];
    }
}

extern "C" void kernel_launch(void* const* d_in, const int* in_sizes, int n_in,
                              void* d_out, int out_size, void* d_ws, size_t ws_size,
                              hipStream_t stream) {
    const float* x  = (const float*)d_in[0];
    const int*   ei = (const int*)d_in[1];   // int32 per harness contract
    const float* W1 = (const float*)d_in[2];
    const float* b1 = (const float*)d_in[3];
    const float* W2 = (const float*)d_in[4];
    const float* b2 = (const float*)d_in[5];
    float* out = (float*)d_out;

    // ws layout: cnt[N] int | cursor[N] int | dinv[N] f32 | z[N] f32 | csr_src[E] int  (~14.4 MB)
    int*   cnt     = (int*)d_ws;
    int*   cursor  = cnt + N_NODES;
    float* dinv    = (float*)(cursor + N_NODES);
    float* z       = dinv + N_NODES;
    int*   csr_src = (int*)(z + N_NODES);

    const int* src = ei;            // edge_index[0]
    const int* dst = ei + N_EDGES;  // edge_index[1]

    const int TB = 256;
    int gE = (N_EDGES + TB - 1) / TB;
    int gW = (N_NODES + 3) / 4;     // 4 waves (nodes) per 256-thread block

    hipMemsetAsync(cnt, 0, N_NODES * sizeof(int), stream);
    hist_kernel<<<gE, TB, 0, stream>>>(dst, cnt);
    scan_kernel<<<1, 1024, 0, stream>>>(cnt, cursor, dinv);
    scatter_kernel<<<gE, TB, 0, stream>>>(src, dst, cursor, csr_src);
    gather1_kernel<<<gW, TB, 0, stream>>>(csr_src, cursor, cnt, dinv, x, W1, b1, W2, z);
    gather2_kernel<<<gW, TB, 0, stream>>>(csr_src, cursor, cnt, dinv, z, b2, out);
}

// Round 13
// 272.368 us; speedup vs baseline: 11.1874x; 2.3951x over previous
//
#include <hip/hip_runtime.h>

// GCN 2-layer via coarse dst-binning + LDS-accumulated gathers.
// R4: per-edge float far-atomics = 2634us wall. R11: per-node CSR build
// (hist 3.2M atomics + scatter 3.2M returning atomics) = ~470us of 652us.
// This version: 1-level radix binning (atomics at block*bin granularity,
// ~196K total) + per-bin LDS accumulators. No per-node CSR.
constexpr int N_NODES = 100000;
constexpr int N_EDGES = 3200000;
constexpr int F1  = 16;   // hidden dim
constexpr int FIN = 5;    // input dim
constexpr int NPB = 200;  // nodes per bin
constexpr int NB  = N_NODES / NPB;  // 500 bins (exact)
constexpr int TILE = 8192;          // edges per reorder tile
constexpr int TB  = 256;

// ---- 1: per-tile LDS histogram of dst-bins -> global bin_cnt ----
__global__ __launch_bounds__(256) void binhist_kernel(const int* __restrict__ dst,
                                                      int* __restrict__ bin_cnt) {
    __shared__ int lh[NB];
    int t = threadIdx.x;
    for (int b = t; b < NB; b += TB) lh[b] = 0;
    __syncthreads();
    int base = blockIdx.x * TILE;
#pragma unroll
    for (int k = 0; k < TILE / TB; ++k) {
        int e = base + k * TB + t;
        if (e < N_EDGES) atomicAdd(&lh[dst[e] / NPB], 1);
    }
    __syncthreads();
    for (int b = t; b < NB; b += TB) {
        int c = lh[b];
        if (c) atomicAdd(&bin_cnt[b], c);
    }
}

// ---- 2: single-block exclusive scan of 500 bin counts ----
__global__ __launch_bounds__(512) void binscan_kernel(const int* __restrict__ bin_cnt,
                                                      int* __restrict__ bin_base,
                                                      int* __restrict__ bin_cursor) {
    __shared__ int buf[2][512];
    int t = threadIdx.x;
    int v = (t < NB) ? bin_cnt[t] : 0;
    buf[0][t] = v;
    __syncthreads();
    int cur = 0;
    for (int off = 1; off < 512; off <<= 1) {
        int nv = buf[cur][t];
        if (t >= off) nv += buf[cur][t - off];
        buf[cur ^ 1][t] = nv;
        cur ^= 1;
        __syncthreads();
    }
    if (t < NB) {
        int excl = buf[cur][t] - v;
        bin_base[t] = excl;
        bin_cursor[t] = excl;
    }
    if (t == 0) bin_base[NB] = N_EDGES;
}

// ---- 3: reorder edges into bins; pack (d_local<<24)|src into one int ----
__global__ __launch_bounds__(256) void reorder_kernel(const int* __restrict__ src,
                                                      const int* __restrict__ dst,
                                                      int* __restrict__ bin_cursor,
                                                      int* __restrict__ binned) {
    __shared__ int lh[NB];
    __shared__ int lbase[NB];
    int t = threadIdx.x;
    for (int b = t; b < NB; b += TB) lh[b] = 0;
    __syncthreads();
    int tile0 = blockIdx.x * TILE;
    // phase 1: local count
#pragma unroll
    for (int k = 0; k < TILE / TB; ++k) {
        int e = tile0 + k * TB + t;
        if (e < N_EDGES) atomicAdd(&lh[dst[e] / NPB], 1);
    }
    __syncthreads();
    // phase 2: reserve global runs (one returning atomic per touched bin)
    for (int b = t; b < NB; b += TB) {
        int c = lh[b];
        lbase[b] = c ? atomicAdd(&bin_cursor[b], c) : 0;
        lh[b] = 0;
    }
    __syncthreads();
    // phase 3: place edges (LDS rank + run-coalesced global write)
#pragma unroll
    for (int k = 0; k < TILE / TB; ++k) {
        int e = tile0 + k * TB + t;
        if (e < N_EDGES) {
            int d = dst[e];
            int b = d / NPB;
            int r = atomicAdd(&lh[b], 1);
            binned[lbase[b] + r] = src[e] | ((d - b * NPB) << 24);
        }
    }
}

// ---- 4: per-bin degree count -> dinv = rsqrt(deg+1) ----
__global__ __launch_bounds__(256) void degbin_kernel(const int* __restrict__ binned,
                                                     const int* __restrict__ bin_base,
                                                     float* __restrict__ dinv) {
    __shared__ int cnt[NPB];
    int t = threadIdx.x;
    int b = blockIdx.x;
    if (t < NPB) cnt[t] = 0;
    __syncthreads();
    int s0 = bin_base[b], s1 = bin_base[b + 1];
    for (int e = s0 + t; e < s1; e += TB)
        atomicAdd(&cnt[((unsigned)binned[e]) >> 24], 1);
    __syncthreads();
    if (t < NPB) dinv[b * NPB + t] = rsqrtf((float)cnt[t] + 1.0f);
}

// ---- 5: layer-1 gather per bin: LDS agg[NPB][5] via LDS float atomics,
//         then z = relu(agg@W1 + b1) @ W2 (aggregation commutes with W1) ----
__global__ __launch_bounds__(256) void gather1_kernel(const int* __restrict__ binned,
                                                      const int* __restrict__ bin_base,
                                                      const float* __restrict__ dinv,
                                                      const float* __restrict__ x,
                                                      const float* __restrict__ W1,
                                                      const float* __restrict__ b1,
                                                      const float* __restrict__ W2,
                                                      float* __restrict__ z) {
    __shared__ float agg[NPB * FIN];
    __shared__ float dinvL[NPB];
    int t = threadIdx.x;
    int b = blockIdx.x;
    int g = b * NPB + t;
    if (t < NPB) {
        float dd = dinv[g];
        dinvL[t] = dd;
        float di2 = dd * dd;
#pragma unroll
        for (int k = 0; k < FIN; ++k) agg[t * FIN + k] = di2 * x[g * FIN + k];
    }
    __syncthreads();
    int s0 = bin_base[b], s1 = bin_base[b + 1];
    for (int e = s0 + t; e < s1; e += TB) {
        int v = binned[e];
        int s = v & 0x00FFFFFF;
        int dl = ((unsigned)v) >> 24;
        float w = dinv[s] * dinvL[dl];
#pragma unroll
        for (int k = 0; k < FIN; ++k)
            atomicAdd(&agg[dl * FIN + k], w * x[s * FIN + k]);
    }
    __syncthreads();
    if (t < NPB) {
        float a[FIN];
#pragma unroll
        for (int k = 0; k < FIN; ++k) a[k] = agg[t * FIN + k];
        float p = 0.f;
#pragma unroll
        for (int f = 0; f < F1; ++f) {
            float h = b1[f];
#pragma unroll
            for (int k = 0; k < FIN; ++k) h += a[k] * W1[k * F1 + f];
            p += fmaxf(h, 0.f) * W2[f];
        }
        z[g] = p;
    }
}

// ---- 6: layer-2 gather per bin: out = dd*(dd*z[d] + sum dinv[s]*z[s]) + b2 ----
__global__ __launch_bounds__(256) void gather2_kernel(const int* __restrict__ binned,
                                                      const int* __restrict__ bin_base,
                                                      const float* __restrict__ dinv,
                                                      const float* __restrict__ z,
                                                      const float* __restrict__ b2,
                                                      float* __restrict__ out) {
    __shared__ float acc[NPB];
    __shared__ float dinvL[NPB];
    int t = threadIdx.x;
    int b = blockIdx.x;
    int g = b * NPB + t;
    if (t < NPB) {
        float dd = dinv[g];
        dinvL[t] = dd;
        acc[t] = dd * z[g];
    }
    __syncthreads();
    int s0 = bin_base[b], s1 = bin_base[b + 1];
    for (int e = s0 + t; e < s1; e += TB) {
        int v = binned[e];
        int s = v & 0x00FFFFFF;
        atomicAdd(&acc[((unsigned)v) >> 24], dinv[s] * z[s]);
    }
    __syncthreads();
    if (t < NPB) out[g] = dinvL[t] * acc[t] + b2[0];
}

extern "C" void kernel_launch(void* const* d_in, const int* in_sizes, int n_in,
                              void* d_out, int out_size, void* d_ws, size_t ws_size,
                              hipStream_t stream) {
    const float* x  = (const float*)d_in[0];
    const int*   ei = (const int*)d_in[1];   // int32 per harness contract
    const float* W1 = (const float*)d_in[2];
    const float* b1 = (const float*)d_in[3];
    const float* W2 = (const float*)d_in[4];
    const float* b2 = (const float*)d_in[5];
    float* out = (float*)d_out;

    // ws: bin_cnt[NB] | bin_base[NB+1] | bin_cursor[NB] | dinv[N] | z[N] | binned[E]  (~13.6 MB)
    int*   bin_cnt    = (int*)d_ws;
    int*   bin_base   = bin_cnt + NB;
    int*   bin_cursor = bin_base + NB + 1;
    float* dinv       = (float*)(bin_cursor + NB);
    float* z          = dinv + N_NODES;
    int*   binned     = (int*)(z + N_NODES);

    const int* src = ei;            // edge_index[0]
    const int* dst = ei + N_EDGES;  // edge_index[1]

    int gT = (N_EDGES + TILE - 1) / TILE;   // 391 reorder tiles

    hipMemsetAsync(bin_cnt, 0, NB * sizeof(int), stream);
    binhist_kernel<<<gT, TB, 0, stream>>>(dst, bin_cnt);
    binscan_kernel<<<1, 512, 0, stream>>>(bin_cnt, bin_base, bin_cursor);
    reorder_kernel<<<gT, TB, 0, stream>>>(src, dst, bin_cursor, binned);
    degbin_kernel<<<NB, TB, 0, stream>>>(binned, bin_base, dinv);
    gather1_kernel<<<NB, TB, 0, stream>>>(binned, bin_base, dinv, x, W1, b1, W2, z);
    gather2_kernel<<<NB, TB, 0, stream>>>(binned, bin_base, dinv, z, b2, out);
}